// Round 17
// baseline (72.174 us; speedup 1.0000x reference)
//
#include <hip/hip_runtime.h>

// Masked SDPA: B=8 H=16 S=1024 D=64, fp32 in, fp32 out.
// Round-17 over round-16: 2-DEEP PREFETCH PIPELINE.
//  Theory: concurrent working set per XCD (~12 panels x 768KB) >> 4MB L2 ->
//  K/V loads are L3-served (~600-1000cy); 1-phase prefetch distance didn't
//  cover it -> every tile stalls on vmcnt. Now: register sets A/B, tile kt
//  stages from set(kt&1) then re-issues that set for kt+2 -> every load has
//  ~2 compute phases (~2000cy) in flight. Loop unrolled x2 (macro, all
//  register-array indices compile-time; rule #20).
//  keeps: per-XCD queues (128B-spaced counters), panel-major items, V-skew,
//  fixed-m softmax (v_exp), mean-V fast path, straddler trim+epilogue,
//  boundary-only masking, partial-lsum, pk2, setprio.

#define Sdim 1024
#define Ddim 64
#define PITCH 72   // u16 per LDS row (64 + 8 pad; rows 16B-aligned for b128)

typedef float f32x4 __attribute__((ext_vector_type(4)));
typedef _Float16 f16x8 __attribute__((ext_vector_type(8)));
typedef unsigned short u16x8 __attribute__((ext_vector_type(8)));
typedef unsigned int u32x2 __attribute__((ext_vector_type(2)));

union FragU { u16x8 u; f16x8 h; };

__device__ __forceinline__ unsigned pk2(float a, float b) {
  auto h = __builtin_amdgcn_cvt_pkrtz(a, b);
  return __builtin_bit_cast(unsigned, h);
}

__device__ __forceinline__ float fexp2(float x) {
  float r;
  asm("v_exp_f32 %0, %1" : "=v"(r) : "v"(x));   // exp2; exp2(-inf)=0
  return r;
}

// One K-tile iteration: stage from register set (KP,VP), re-issue that set
// for tile KT+2, then compute. All KP/VP indices are literals.
#define DO_TILE(KP, VP, LOADFN, KT)                                          \
  do {                                                                       \
    const int k0 = (KT) * 64;                                                \
    __syncthreads();                                                         \
    _Pragma("unroll")                                                        \
    for (int i = 0; i < 4; ++i) {                                            \
      u32x2 o;                                                               \
      o[0] = pk2(KP[i].x, KP[i].y); o[1] = pk2(KP[i].z, KP[i].w);            \
      *(u32x2*)&k_lds[(16 * i + sr) * PITCH + sc * 4] = o;                   \
    }                                                                        \
    {                                                                        \
      const int cp = (sr * 4 + vskew) & 63;                                  \
      u32x2 o;                                                               \
      o[0] = pk2(VP[0].x, VP[1].x); o[1] = pk2(VP[2].x, VP[3].x);            \
      *(u32x2*)&v_lds[(sc * 4 + 0) * PITCH + cp] = o;                        \
      o[0] = pk2(VP[0].y, VP[1].y); o[1] = pk2(VP[2].y, VP[3].y);            \
      *(u32x2*)&v_lds[(sc * 4 + 1) * PITCH + cp] = o;                        \
      o[0] = pk2(VP[0].z, VP[1].z); o[1] = pk2(VP[2].z, VP[3].z);            \
      *(u32x2*)&v_lds[(sc * 4 + 2) * PITCH + cp] = o;                        \
      o[0] = pk2(VP[0].w, VP[1].w); o[1] = pk2(VP[2].w, VP[3].w);            \
      *(u32x2*)&v_lds[(sc * 4 + 3) * PITCH + cp] = o;                        \
    }                                                                        \
    __syncthreads();                                                         \
    if ((KT) + 2 < kFull) LOADFN((KT) * 64 + 128);                           \
    if (wValid) {                                                            \
      f32x4 sacc[2][4];                                                      \
      _Pragma("unroll")                                                      \
      for (int qc = 0; qc < 2; ++qc)                                         \
        _Pragma("unroll")                                                    \
        for (int kc = 0; kc < 4; ++kc) sacc[qc][kc] = zero4;                 \
      __builtin_amdgcn_s_setprio(1);                                         \
      _Pragma("unroll")                                                      \
      for (int kc = 0; kc < 4; ++kc)                                         \
        _Pragma("unroll")                                                    \
        for (int kk = 0; kk < 2; ++kk) {                                     \
          FragU kf;                                                          \
          kf.u = *(const u16x8*)&k_lds[(kc * 16 + r) * PITCH + kk * 32 + hi * 8]; \
          sacc[0][kc] = __builtin_amdgcn_mfma_f32_16x16x32_f16(kf.h, qf[0][kk], sacc[0][kc], 0, 0, 0); \
          sacc[1][kc] = __builtin_amdgcn_mfma_f32_16x16x32_f16(kf.h, qf[1][kk], sacc[1][kc], 0, 0, 0); \
        }                                                                    \
      __builtin_amdgcn_s_setprio(0);                                         \
      const bool noMask = wAllVal && ((KT) != ktB);                          \
      _Pragma("unroll")                                                      \
      for (int qc = 0; qc < 2; ++qc) {                                       \
        const bool qv = qc ? qv1 : qv0;                                      \
        float ls = 0.f;                                                      \
        _Pragma("unroll")                                                    \
        for (int kc = 0; kc < 4; ++kc) {                                     \
          float pr[4];                                                       \
          _Pragma("unroll")                                                  \
          for (int rg = 0; rg < 4; ++rg) {                                   \
            float s = sacc[qc][kc][rg];                                      \
            if (!noMask) {                                                   \
              int kg = k0 + kc * 16 + 4 * hi + rg;                           \
              s = (qv && kg < L) ? s : -__builtin_inff();                    \
            }                                                                \
            pr[rg] = fexp2(s);                                               \
            ls += pr[rg];                                                    \
          }                                                                  \
          u32x2 o;                                                           \
          o[0] = pk2(pr[0], pr[1]);                                          \
          o[1] = pk2(pr[2], pr[3]);                                          \
          *(u32x2*)&p_lds[w][(qc * 16 + r) * PITCH + kc * 16 + 4 * hi] = o;  \
        }                                                                    \
        lpart[qc] += ls;                                                     \
      }                                                                      \
      asm volatile("s_waitcnt lgkmcnt(0)" ::: "memory");                     \
      __builtin_amdgcn_sched_barrier(0);                                     \
      __builtin_amdgcn_s_setprio(1);                                         \
      _Pragma("unroll")                                                      \
      for (int ks = 0; ks < 2; ++ks) {                                       \
        FragU pf0, pf1;                                                      \
        pf0.u = *(const u16x8*)&p_lds[w][(0  + r) * PITCH + ks * 32 + hi * 8]; \
        pf1.u = *(const u16x8*)&p_lds[w][(16 + r) * PITCH + ks * 32 + hi * 8]; \
        _Pragma("unroll")                                                    \
        for (int dc = 0; dc < 4; ++dc) {                                     \
          const int vcp = (ks * 32 + hi * 8 + (((dc * 2 + r3) & 7) << 3)) & 63; \
          FragU vf;                                                          \
          vf.u = *(const u16x8*)&v_lds[(dc * 16 + r) * PITCH + vcp];         \
          oacc[0][dc] = __builtin_amdgcn_mfma_f32_16x16x32_f16(pf0.h, vf.h, oacc[0][dc], 0, 0, 0); \
          oacc[1][dc] = __builtin_amdgcn_mfma_f32_16x16x32_f16(pf1.h, vf.h, oacc[1][dc], 0, 0, 0); \
        }                                                                    \
      }                                                                      \
      __builtin_amdgcn_s_setprio(0);                                         \
    }                                                                        \
  } while (0)

__global__ __launch_bounds__(256, 3)
void attn_fwd(const float* __restrict__ Q, const float* __restrict__ K,
              const float* __restrict__ V, const int* __restrict__ EL,
              float* __restrict__ Out, unsigned* __restrict__ queues) {
  __shared__ unsigned short k_lds[64 * PITCH];        // [k][d] f16
  __shared__ unsigned short v_lds[64 * PITCH];        // [d][k] f16, k-skewed
  __shared__ unsigned short p_lds[4][32 * PITCH];     // per-wave [q][k] f16
  __shared__ int s_item;

  const int tid   = threadIdx.x;
  const int homeq = blockIdx.x & 7;    // HW round-robin -> home XCD
  unsigned* ctr = &queues[homeq * 32]; // 128B-spaced counters

  const int w    = tid >> 6;
  const int lane = tid & 63;
  const int r    = lane & 15;
  const int hi   = lane >> 4;
  const int r3   = r >> 3;
  const int sr   = tid >> 4;           // 0..15
  const int sc   = tid & 15;
  const int vskew = ((sc >> 1) & 7) * 8;

  for (;;) {
    __syncthreads();                   // prev item's LDS reads complete
    if (tid == 0) s_item = (int)atomicAdd(ctr, 1u);
    __syncthreads();
    const int g = s_item;
    if (g >= 128) break;

    const int pan = g >> 3;
    const int qt  = g & 7;
    const int bh  = pan * 8 + homeq;
    const int L   = EL[bh >> 4];

    const size_t base = (size_t)bh * Sdim * Ddim;
    const float* Qb = Q + base;
    const float* Kb = K + base;
    const float* Vb = V + base;
    float* ob = Out + base;

    const int q0blk = qt * 128;

    // ============ mean-V fast path: entire block invalid ============
    if (q0blk >= L) {
      float* red = (float*)k_lds;
      const int sc4 = sc * 4;
      const float* vp = Vb + (size_t)sr * Ddim + sc4;
      float4 acc = {0.f, 0.f, 0.f, 0.f};
#pragma unroll 8
      for (int i = 0; i < 64; ++i) {
        float4 a = *(const float4*)(vp + (size_t)i * 16 * Ddim);
        acc.x += a.x; acc.y += a.y; acc.z += a.z; acc.w += a.w;
      }
      *(float4*)&red[sr * 68 + sc4] = acc;
      __syncthreads();
      if (tid < 16) {
        float4 s = {0.f, 0.f, 0.f, 0.f};
#pragma unroll
        for (int i = 0; i < 16; ++i) {
          float4 a = *(const float4*)&red[i * 68 + tid * 4];
          s.x += a.x; s.y += a.y; s.z += a.z; s.w += a.w;
        }
        const float inv = 1.0f / 1024.0f;
        s.x *= inv; s.y *= inv; s.z *= inv; s.w *= inv;
        *(float4*)&red[16 * 68 + tid * 4] = s;
      }
      __syncthreads();
      const float4 cm = *(const float4*)&red[16 * 68 + sc4];
#pragma unroll
      for (int pp = 0; pp < 8; ++pp) {
        int row = q0blk + pp * 16 + sr;
        *(float4*)&ob[(size_t)row * Ddim + sc4] = cm;
      }
      continue;
    }

    // ===================== main flash path =====================
    const int q0w      = q0blk + w * 32;
    const bool wValid  = q0w < L;
    const bool wAllVal = (q0w + 32) <= L;
    const int kFull    = (L + 63) >> 6;
    const int ktB      = L >> 6;
    const bool straddle = (q0blk + 128) > L;

    const bool qv0 = (q0w + r) < L;
    const bool qv1 = (q0w + 16 + r) < L;

    const float SCL = 0.125f * 1.44269504088896340736f;
    f16x8 qf[2][2];
    if (wValid) {
#pragma unroll
      for (int qc = 0; qc < 2; ++qc)
#pragma unroll
        for (int kk = 0; kk < 2; ++kk) {
          const float* pq = Qb + (size_t)(q0w + qc * 16 + r) * Ddim + kk * 32 + hi * 8;
          float4 a = *(const float4*)pq;
          float4 cc = *(const float4*)(pq + 4);
          union { unsigned u[4]; f16x8 hh; } f;
          f.u[0] = pk2(a.x * SCL, a.y * SCL);   f.u[1] = pk2(a.z * SCL, a.w * SCL);
          f.u[2] = pk2(cc.x * SCL, cc.y * SCL); f.u[3] = pk2(cc.z * SCL, cc.w * SCL);
          qf[qc][kk] = f.hh;
        }
    }

    const f32x4 zero4 = {0.f, 0.f, 0.f, 0.f};
    f32x4 oacc[2][4];
#pragma unroll
    for (int qc = 0; qc < 2; ++qc)
#pragma unroll
      for (int dc = 0; dc < 4; ++dc) oacc[qc][dc] = zero4;

    float lpart[2] = {0.f, 0.f};

    const float* pK = Kb + (size_t)sr * Ddim + sc * 4;
    const float* pV = Vb + (size_t)(sr * 4) * Ddim + sc * 4;

    float4 kpreA[4], vpreA[4], kpreB[4], vpreB[4];
    auto LOADA = [&](int k0_) {
#pragma unroll
      for (int i = 0; i < 4; ++i)
        kpreA[i] = *(const float4*)(pK + (size_t)(k0_ + 16 * i) * Ddim);
#pragma unroll
      for (int jj = 0; jj < 4; ++jj)
        vpreA[jj] = *(const float4*)(pV + (size_t)(k0_ + jj) * Ddim);
    };
    auto LOADB = [&](int k0_) {
#pragma unroll
      for (int i = 0; i < 4; ++i)
        kpreB[i] = *(const float4*)(pK + (size_t)(k0_ + 16 * i) * Ddim);
#pragma unroll
      for (int jj = 0; jj < 4; ++jj)
        vpreB[jj] = *(const float4*)(pV + (size_t)(k0_ + jj) * Ddim);
    };

    LOADA(0);
    if (kFull > 1) LOADB(64);

    for (int kt = 0; kt < kFull; kt += 2) {
      DO_TILE(kpreA, vpreA, LOADA, kt);
      if (kt + 1 < kFull) DO_TILE(kpreB, vpreB, LOADB, kt + 1);
    }

    // ---- epilogue: valid rows: divide by row sum, write fp32 ----
#pragma unroll
    for (int qc = 0; qc < 2; ++qc) {
      float l = lpart[qc];
      l += __shfl_xor(l, 16, 64);
      l += __shfl_xor(l, 32, 64);
#pragma unroll
      for (int rg = 0; rg < 4; ++rg) {
        float lsq = __shfl(l, 4 * hi + rg, 64);
        float inv = 1.0f / lsq;
        int qrow = q0w + qc * 16 + 4 * hi + rg;
        if (qrow < L) {
#pragma unroll
          for (int dc = 0; dc < 4; ++dc)
            ob[(size_t)qrow * Ddim + dc * 16 + r] = oacc[qc][dc][rg] * inv;
        }
      }
    }

    // ---- straddler epilogue: rows >= L get colmean(V) ----
    if (straddle) {
      __syncthreads();
      float* red = (float*)k_lds;
      const int sc4 = sc * 4;
      const float* vp = Vb + (size_t)sr * Ddim + sc4;
      float4 acc = {0.f, 0.f, 0.f, 0.f};
#pragma unroll 8
      for (int i = 0; i < 64; ++i) {
        float4 a = *(const float4*)(vp + (size_t)i * 16 * Ddim);
        acc.x += a.x; acc.y += a.y; acc.z += a.z; acc.w += a.w;
      }
      *(float4*)&red[sr * 68 + sc4] = acc;
      __syncthreads();
      if (tid < 16) {
        float4 s = {0.f, 0.f, 0.f, 0.f};
#pragma unroll
        for (int i = 0; i < 16; ++i) {
          float4 a = *(const float4*)&red[i * 68 + tid * 4];
          s.x += a.x; s.y += a.y; s.z += a.z; s.w += a.w;
        }
        const float inv = 1.0f / 1024.0f;
        s.x *= inv; s.y *= inv; s.z *= inv; s.w *= inv;
        *(float4*)&red[16 * 68 + tid * 4] = s;
      }
      __syncthreads();
      const float4 cm = *(const float4*)&red[16 * 68 + sc4];
#pragma unroll
      for (int pp = 0; pp < 8; ++pp) {
        int row = q0blk + pp * 16 + sr;
        if (row >= L)
          *(float4*)&ob[(size_t)row * Ddim + sc4] = cm;
      }
    }
  }
}

extern "C" void kernel_launch(void* const* d_in, const int* in_sizes, int n_in,
                              void* d_out, int out_size, void* d_ws, size_t ws_size,
                              hipStream_t stream) {
  const float* q  = (const float*)d_in[0];
  const float* k  = (const float*)d_in[1];
  const float* v  = (const float*)d_in[2];
  const int*   el = (const int*)d_in[3];
  float* out = (float*)d_out;
  hipMemsetAsync(d_ws, 0, 1024, stream);
  dim3 grid(768);    // 3 persistent blocks/CU; 96 blocks per XCD queue
  dim3 block(256);
  hipLaunchKernelGGL(attn_fwd, grid, block, 0, stream, q, k, v, el, out,
                     (unsigned*)d_ws);
}

// Round 18
// 48.235 us; speedup vs baseline: 1.4963x; 1.4963x over previous
//
#include <hip/hip_runtime.h>

// Masked SDPA: B=8 H=16 S=1024 D=64, fp32 in, fp32 out.
// Round-18 over round-16 (R17's reg-pipeline spilled: WRITE 33->85MB):
//  - DOUBLE-BUFFERED LDS pipeline (spill-free 2-deep): tile kt writes
//    kbuf/vbuf[kt&1], issues loads(kt+1) into the single reg set, ONE
//    barrier, computes from buf[kt&1]. Loads get a full tile phase to land;
//    barriers/drains per tile halve. Buffer-reuse safety: next write to a
//    buffer is 2 tiles later, past a barrier whose predecessors drained
//    their ds_reads (compiler emits lgkmcnt(0) before s_barrier).
//  - LDS 55.3KB -> 2 blocks/CU; grid 512 persistent; launch_bounds(256,2).
//  - keeps: per-XCD queues (128B-spaced), panel-major items, V-skew,
//    fixed-m softmax (v_exp), mean-V fast path, straddler trim+epilogue,
//    boundary-only masking, partial-lsum, pk2, setprio.

#define Sdim 1024
#define Ddim 64
#define PITCH 72   // u16 per LDS row (64 + 8 pad; rows 16B-aligned for b128)

typedef float f32x4 __attribute__((ext_vector_type(4)));
typedef _Float16 f16x8 __attribute__((ext_vector_type(8)));
typedef unsigned short u16x8 __attribute__((ext_vector_type(8)));
typedef unsigned int u32x2 __attribute__((ext_vector_type(2)));

union FragU { u16x8 u; f16x8 h; };

__device__ __forceinline__ unsigned pk2(float a, float b) {
  auto h = __builtin_amdgcn_cvt_pkrtz(a, b);
  return __builtin_bit_cast(unsigned, h);
}

__device__ __forceinline__ float fexp2(float x) {
  float r;
  asm("v_exp_f32 %0, %1" : "=v"(r) : "v"(x));   // exp2; exp2(-inf)=0
  return r;
}

__global__ __launch_bounds__(256, 2)
void attn_fwd(const float* __restrict__ Q, const float* __restrict__ K,
              const float* __restrict__ V, const int* __restrict__ EL,
              float* __restrict__ Out, unsigned* __restrict__ queues) {
  __shared__ unsigned short kbuf[2][64 * PITCH];      // [k][d] f16
  __shared__ unsigned short vbuf[2][64 * PITCH];      // [d][k] f16, k-skewed
  __shared__ unsigned short p_lds[4][32 * PITCH];     // per-wave [q][k] f16
  __shared__ int s_item;

  const int tid   = threadIdx.x;
  const int homeq = blockIdx.x & 7;    // HW round-robin -> home XCD
  unsigned* ctr = &queues[homeq * 32]; // 128B-spaced counters

  const int w    = tid >> 6;
  const int lane = tid & 63;
  const int r    = lane & 15;
  const int hi   = lane >> 4;
  const int r3   = r >> 3;
  const int sr   = tid >> 4;           // 0..15
  const int sc   = tid & 15;
  const int vskew = ((sc >> 1) & 7) * 8;   // = ((d>>3)&7)*8 for d=sc*4+cc

  for (;;) {
    __syncthreads();                   // prev item's LDS reads complete
    if (tid == 0) s_item = (int)atomicAdd(ctr, 1u);
    __syncthreads();
    const int g = s_item;
    if (g >= 128) break;

    const int pan = g >> 3;            // panel-major: 8 q-tiles drain together
    const int qt  = g & 7;
    const int bh  = pan * 8 + homeq;
    const int L   = EL[bh >> 4];

    const size_t base = (size_t)bh * Sdim * Ddim;
    const float* Qb = Q + base;
    const float* Kb = K + base;
    const float* Vb = V + base;
    float* ob = Out + base;

    const int q0blk = qt * 128;

    // ============ mean-V fast path: entire block invalid ============
    // rows >= L: -1e9 on every fp32 score -> absorption -> exactly
    // uniform softmax -> out = colmean(V).
    if (q0blk >= L) {
      float* red = (float*)&kbuf[0][0];
      const int sc4 = sc * 4;
      const float* vp = Vb + (size_t)sr * Ddim + sc4;
      float4 acc = {0.f, 0.f, 0.f, 0.f};
#pragma unroll 8
      for (int i = 0; i < 64; ++i) {
        float4 a = *(const float4*)(vp + (size_t)i * 16 * Ddim);
        acc.x += a.x; acc.y += a.y; acc.z += a.z; acc.w += a.w;
      }
      *(float4*)&red[sr * 68 + sc4] = acc;
      __syncthreads();
      if (tid < 16) {
        float4 s = {0.f, 0.f, 0.f, 0.f};
#pragma unroll
        for (int i = 0; i < 16; ++i) {
          float4 a = *(const float4*)&red[i * 68 + tid * 4];
          s.x += a.x; s.y += a.y; s.z += a.z; s.w += a.w;
        }
        const float inv = 1.0f / 1024.0f;
        s.x *= inv; s.y *= inv; s.z *= inv; s.w *= inv;
        *(float4*)&red[16 * 68 + tid * 4] = s;
      }
      __syncthreads();
      const float4 cm = *(const float4*)&red[16 * 68 + sc4];
#pragma unroll
      for (int pp = 0; pp < 8; ++pp) {
        int row = q0blk + pp * 16 + sr;
        *(float4*)&ob[(size_t)row * Ddim + sc4] = cm;
      }
      continue;
    }

    // ===================== main flash path =====================
    const int q0w      = q0blk + w * 32;
    const bool wValid  = q0w < L;
    const bool wAllVal = (q0w + 32) <= L;
    const int kFull    = (L + 63) >> 6;
    const int ktB      = L >> 6;
    const bool straddle = (q0blk + 128) > L;

    const bool qv0 = (q0w + r) < L;
    const bool qv1 = (q0w + 16 + r) < L;

    // Q fragments, pre-scaled by 1/sqrt(D)*log2(e)
    const float SCL = 0.125f * 1.44269504088896340736f;
    f16x8 qf[2][2];
    if (wValid) {
#pragma unroll
      for (int qc = 0; qc < 2; ++qc)
#pragma unroll
        for (int kk = 0; kk < 2; ++kk) {
          const float* pq = Qb + (size_t)(q0w + qc * 16 + r) * Ddim + kk * 32 + hi * 8;
          float4 a = *(const float4*)pq;
          float4 cc = *(const float4*)(pq + 4);
          union { unsigned u[4]; f16x8 hh; } f;
          f.u[0] = pk2(a.x * SCL, a.y * SCL);   f.u[1] = pk2(a.z * SCL, a.w * SCL);
          f.u[2] = pk2(cc.x * SCL, cc.y * SCL); f.u[3] = pk2(cc.z * SCL, cc.w * SCL);
          qf[qc][kk] = f.hh;
        }
    }

    const f32x4 zero4 = {0.f, 0.f, 0.f, 0.f};
    f32x4 oacc[2][4];
#pragma unroll
    for (int qc = 0; qc < 2; ++qc)
#pragma unroll
      for (int dc = 0; dc < 4; ++dc) oacc[qc][dc] = zero4;

    float lpart[2] = {0.f, 0.f};

    const float* pK = Kb + (size_t)sr * Ddim + sc * 4;
    const float* pV = Vb + (size_t)(sr * 4) * Ddim + sc * 4;

    float4 kpre[4], vpre[4];
    auto LOADK = [&](int k0_) {
#pragma unroll
      for (int i = 0; i < 4; ++i)
        kpre[i] = *(const float4*)(pK + (size_t)(k0_ + 16 * i) * Ddim);
    };
    auto LOADV = [&](int k0_) {
#pragma unroll
      for (int jj = 0; jj < 4; ++jj)
        vpre[jj] = *(const float4*)(pV + (size_t)(k0_ + jj) * Ddim);
    };

    LOADK(0);
    LOADV(0);

    for (int kt = 0; kt < kFull; ++kt) {
      const int k0 = kt * 64;
      unsigned short* k_lds = &kbuf[kt & 1][0];
      unsigned short* v_lds = &vbuf[kt & 1][0];

      // stage tile kt into buf[kt&1] (regs were loaded last iteration)
#pragma unroll
      for (int i = 0; i < 4; ++i) {
        u32x2 o;
        o[0] = pk2(kpre[i].x, kpre[i].y); o[1] = pk2(kpre[i].z, kpre[i].w);
        *(u32x2*)&k_lds[(16 * i + sr) * PITCH + sc * 4] = o;
      }
      {
        const int cp = (sr * 4 + vskew) & 63;
        u32x2 o;
        o[0] = pk2(vpre[0].x, vpre[1].x); o[1] = pk2(vpre[2].x, vpre[3].x);
        *(u32x2*)&v_lds[(sc * 4 + 0) * PITCH + cp] = o;
        o[0] = pk2(vpre[0].y, vpre[1].y); o[1] = pk2(vpre[2].y, vpre[3].y);
        *(u32x2*)&v_lds[(sc * 4 + 1) * PITCH + cp] = o;
        o[0] = pk2(vpre[0].z, vpre[1].z); o[1] = pk2(vpre[2].z, vpre[3].z);
        *(u32x2*)&v_lds[(sc * 4 + 2) * PITCH + cp] = o;
        o[0] = pk2(vpre[0].w, vpre[1].w); o[1] = pk2(vpre[2].w, vpre[3].w);
        *(u32x2*)&v_lds[(sc * 4 + 3) * PITCH + cp] = o;
      }

      // issue next tile's loads (land during this tile's compute + next stage)
      if (kt + 1 < kFull) { LOADK(k0 + 64); LOADV(k0 + 64); }

      __syncthreads();   // one barrier per tile: writes visible, prev reads done

      if (wValid) {
        // ---- QK^T (swapped: A=K rows, B=Q^T) ----
        f32x4 sacc[2][4];
#pragma unroll
        for (int qc = 0; qc < 2; ++qc)
#pragma unroll
          for (int kc = 0; kc < 4; ++kc) sacc[qc][kc] = zero4;

        __builtin_amdgcn_s_setprio(1);
#pragma unroll
        for (int kc = 0; kc < 4; ++kc)
#pragma unroll
          for (int kk = 0; kk < 2; ++kk) {
            FragU kf;
            kf.u = *(const u16x8*)&k_lds[(kc * 16 + r) * PITCH + kk * 32 + hi * 8];
            sacc[0][kc] = __builtin_amdgcn_mfma_f32_16x16x32_f16(kf.h, qf[0][kk], sacc[0][kc], 0, 0, 0);
            sacc[1][kc] = __builtin_amdgcn_mfma_f32_16x16x32_f16(kf.h, qf[1][kk], sacc[1][kc], 0, 0, 0);
          }
        __builtin_amdgcn_s_setprio(0);

        // ---- fixed-m softmax: P = exp2(s); invalid rows -> P = 0 ----
        const bool noMask = wAllVal && (kt != ktB);
#pragma unroll
        for (int qc = 0; qc < 2; ++qc) {
          const bool qv = qc ? qv1 : qv0;
          float ls = 0.f;
#pragma unroll
          for (int kc = 0; kc < 4; ++kc) {
            float pr[4];
#pragma unroll
            for (int rg = 0; rg < 4; ++rg) {
              float s = sacc[qc][kc][rg];
              if (!noMask) {
                int kg = k0 + kc * 16 + 4 * hi + rg;
                s = (qv && kg < L) ? s : -__builtin_inff();
              }
              pr[rg] = fexp2(s);
              ls += pr[rg];
            }
            u32x2 o;
            o[0] = pk2(pr[0], pr[1]);
            o[1] = pk2(pr[2], pr[3]);
            *(u32x2*)&p_lds[w][(qc * 16 + r) * PITCH + kc * 16 + 4 * hi] = o;
          }
          lpart[qc] += ls;
        }

        // P writes -> P reads same-wave: drain LDS queue, pin order
        asm volatile("s_waitcnt lgkmcnt(0)" ::: "memory");
        __builtin_amdgcn_sched_barrier(0);

        // ---- PV: A = P[q][k], B = V[k][d] (skewed v_lds) ----
        __builtin_amdgcn_s_setprio(1);
#pragma unroll
        for (int ks = 0; ks < 2; ++ks) {
          FragU pf0, pf1;
          pf0.u = *(const u16x8*)&p_lds[w][(0  + r) * PITCH + ks * 32 + hi * 8];
          pf1.u = *(const u16x8*)&p_lds[w][(16 + r) * PITCH + ks * 32 + hi * 8];
#pragma unroll
          for (int dc = 0; dc < 4; ++dc) {
            const int vcp = (ks * 32 + hi * 8 + (((dc * 2 + r3) & 7) << 3)) & 63;
            FragU vf;
            vf.u = *(const u16x8*)&v_lds[(dc * 16 + r) * PITCH + vcp];
            oacc[0][dc] = __builtin_amdgcn_mfma_f32_16x16x32_f16(pf0.h, vf.h, oacc[0][dc], 0, 0, 0);
            oacc[1][dc] = __builtin_amdgcn_mfma_f32_16x16x32_f16(pf1.h, vf.h, oacc[1][dc], 0, 0, 0);
          }
        }
        __builtin_amdgcn_s_setprio(0);
      }
    }

    // ---- epilogue: valid rows: divide by row sum, write fp32 ----
#pragma unroll
    for (int qc = 0; qc < 2; ++qc) {
      float l = lpart[qc];
      l += __shfl_xor(l, 16, 64);
      l += __shfl_xor(l, 32, 64);
#pragma unroll
      for (int rg = 0; rg < 4; ++rg) {
        float lsq = __shfl(l, 4 * hi + rg, 64);
        float inv = 1.0f / lsq;
        int qrow = q0w + qc * 16 + 4 * hi + rg;
        if (qrow < L) {
#pragma unroll
          for (int dc = 0; dc < 4; ++dc)
            ob[(size_t)qrow * Ddim + dc * 16 + r] = oacc[qc][dc][rg] * inv;
        }
      }
    }

    // ---- straddler epilogue: rows >= L get colmean(V) ----
    if (straddle) {
      __syncthreads();                 // main loop done with kbuf
      float* red = (float*)&kbuf[0][0];
      const int sc4 = sc * 4;
      const float* vp = Vb + (size_t)sr * Ddim + sc4;
      float4 acc = {0.f, 0.f, 0.f, 0.f};
#pragma unroll 8
      for (int i = 0; i < 64; ++i) {
        float4 a = *(const float4*)(vp + (size_t)i * 16 * Ddim);
        acc.x += a.x; acc.y += a.y; acc.z += a.z; acc.w += a.w;
      }
      *(float4*)&red[sr * 68 + sc4] = acc;
      __syncthreads();
      if (tid < 16) {
        float4 s = {0.f, 0.f, 0.f, 0.f};
#pragma unroll
        for (int i = 0; i < 16; ++i) {
          float4 a = *(const float4*)&red[i * 68 + tid * 4];
          s.x += a.x; s.y += a.y; s.z += a.z; s.w += a.w;
        }
        const float inv = 1.0f / 1024.0f;
        s.x *= inv; s.y *= inv; s.z *= inv; s.w *= inv;
        *(float4*)&red[16 * 68 + tid * 4] = s;
      }
      __syncthreads();
      const float4 cm = *(const float4*)&red[16 * 68 + sc4];
#pragma unroll
      for (int pp = 0; pp < 8; ++pp) {
        int row = q0blk + pp * 16 + sr;
        if (row >= L)
          *(float4*)&ob[(size_t)row * Ddim + sc4] = cm;
      }
    }
  }
}

extern "C" void kernel_launch(void* const* d_in, const int* in_sizes, int n_in,
                              void* d_out, int out_size, void* d_ws, size_t ws_size,
                              hipStream_t stream) {
  const float* q  = (const float*)d_in[0];
  const float* k  = (const float*)d_in[1];
  const float* v  = (const float*)d_in[2];
  const int*   el = (const int*)d_in[3];
  float* out = (float*)d_out;
  hipMemsetAsync(d_ws, 0, 1024, stream);
  dim3 grid(512);    // 2 persistent blocks/CU; 64 blocks per XCD queue
  dim3 block(256);
  hipLaunchKernelGGL(attn_fwd, grid, block, 0, stream, q, k, v, el, out,
                     (unsigned*)d_ws);
}